// Round 7
// baseline (772.761 us; speedup 1.0000x reference)
//
#include <hip/hip_runtime.h>
#include <hip/hip_bf16.h>
#include <stdint.h>

#define DIM   512
#define BATCH 64
#define KENC  1024          // encoded row: 512 interleaved (hi,lo) ushort pairs
#define BM    256
#define BN    256
#define BKT   32
#define NKT   16
#define BUFE  32768         // ushorts per LDS buffer (64 KB): A[256][64] + B[256][64]

typedef __attribute__((ext_vector_type(8))) short short8;
typedef __attribute__((ext_vector_type(4))) float floatx4;

__device__ __forceinline__ ushort f2bf(float f) {
    __hip_bfloat16 h = __float2bfloat16(f);
    return *(ushort*)&h;
}
__device__ __forceinline__ float bf2f(ushort u) {
    __hip_bfloat16 h = *(__hip_bfloat16*)&u;
    return (float)h;
}

typedef __attribute__((address_space(3))) uint32_t lds_u32;
typedef const __attribute__((address_space(1))) uint32_t glb_u32;
__device__ __forceinline__ void gload16(const ushort* g, ushort* l) {
    __builtin_amdgcn_global_load_lds((glb_u32*)g, (lds_u32*)l, 16, 0, 0);
}

#define WAITVM(N) asm volatile("s_waitcnt vmcnt(" #N ")" ::: "memory")
#define BARRIER() do { __builtin_amdgcn_s_barrier(); __builtin_amdgcn_sched_barrier(0); } while (0)

__global__ __launch_bounds__(256) void norm_partial_kernel(const float* __restrict__ x,
                                                           float* __restrict__ partial) {
    int b = blockIdx.y;
    int i = blockIdx.x;
    const float4* xv = (const float4*)(x + (size_t)b * DIM * DIM + (size_t)i * (DIM * DIM / 16));
    float s = 0.f;
    #pragma unroll
    for (int r = 0; r < 16; ++r) {
        float4 v = xv[r * 256 + threadIdx.x];
        s += v.x * v.x + v.y * v.y + v.z * v.z + v.w * v.w;
    }
    #pragma unroll
    for (int off = 32; off > 0; off >>= 1) s += __shfl_down(s, off, 64);
    __shared__ float red[4];
    int lane = threadIdx.x & 63, wid = threadIdx.x >> 6;
    if (lane == 0) red[wid] = s;
    __syncthreads();
    if (threadIdx.x == 0) partial[b * 16 + i] = red[0] + red[1] + red[2] + red[3];
}

__global__ __launch_bounds__(256) void init_kernel(const float* __restrict__ x,
                                                   const float* __restrict__ partial,
                                                   float* __restrict__ norms,
                                                   ushort* __restrict__ Yenc,
                                                   ushort* __restrict__ Tenc) {
    int b = blockIdx.y;
    float s = 0.f;
    #pragma unroll
    for (int p = 0; p < 16; ++p) s += partial[b * 16 + p];
    float nrm = sqrtf(s);
    if (blockIdx.x == 0 && threadIdx.x == 0) norms[b] = nrm;
    float inv = 1.0f / nrm;
    int idx = (blockIdx.x * 256 + threadIdx.x) * 4;
    int r = idx >> 9;
    int c = idx & 511;
    float4 v = *(const float4*)(x + (size_t)b * DIM * DIM + idx);
    float yv[4] = {v.x * inv, v.y * inv, v.z * inv, v.w * inv};
    size_t base = (size_t)b * DIM * KENC + (size_t)r * KENC;
    ushort yp[8], tp[8];   // interleaved (hi,lo) pairs for 4 consecutive elements
    #pragma unroll
    for (int j = 0; j < 4; ++j) {
        float y = yv[j];
        ushort yh = f2bf(y);
        yp[2 * j]     = yh;
        yp[2 * j + 1] = f2bf(y - bf2f(yh));
        float t = ((c + j) == r ? 1.5f : 0.0f) - 0.5f * y;
        ushort th = f2bf(t);
        tp[2 * j]     = th;
        tp[2 * j + 1] = f2bf(t - bf2f(th));
    }
    *(short8*)(Yenc + base + 2 * c) = *(short8*)yp;   // one 16B store each
    *(short8*)(Tenc + base + 2 * c) = *(short8*)tp;
}

// Stage one K-tile (A and B, interleaved pairs) into one LDS buffer: 8 gloads/thread.
// Layout: A rows at buf[row*64 + chunk*8], B at buf[16384 + ...]. Row r's 8 chunks
// of 8 ushorts: physical chunk pc holds logical chunk pc ^ (r&7)  (bank de-alias,
// involution). LDS dest = base + vt*16B (lane-ordered, DMA-legal); the XOR is
// applied on the GLOBAL source address (pre-swizzled-source pattern).
__device__ __forceinline__ void stage_tile(ushort* buf, const ushort* Ag, const ushort* Bg,
                                           int k0, int tid) {
    #pragma unroll
    for (int s = 0; s < 4; ++s) {
        int vt  = tid + s * 512;
        int row = vt >> 3;
        int pc  = vt & 7;
        int kc  = pc ^ (row & 7);
        size_t go = (size_t)row * KENC + 2 * k0 + kc * 8;
        gload16(Ag + go, &buf[vt * 8]);
        gload16(Bg + go, &buf[16384 + vt * 8]);
    }
}

// Read one (hi,lo) fragment pair: two ds_read_b128 of interleaved pairs, then
// v_perm unpack into hi-frag [h0..h7] and lo-frag [l0..l7].
__device__ __forceinline__ uint32_t prm(uint32_t hi, uint32_t lo, uint32_t sel) {
    return __builtin_amdgcn_perm(hi, lo, sel);
}
__device__ __forceinline__ void rdpair(const ushort* rowbase, int q, int r7,
                                       short8& h, short8& l) {
    const uint4 u0 = *(const uint4*)(rowbase + (((2 * q)     ^ r7) << 3));
    const uint4 u1 = *(const uint4*)(rowbase + (((2 * q + 1) ^ r7) << 3));
    uint4 rh, rl;
    rh.x = prm(u0.y, u0.x, 0x05040100u); rh.y = prm(u0.w, u0.z, 0x05040100u);
    rh.z = prm(u1.y, u1.x, 0x05040100u); rh.w = prm(u1.w, u1.z, 0x05040100u);
    rl.x = prm(u0.y, u0.x, 0x07060302u); rl.y = prm(u0.w, u0.z, 0x07060302u);
    rl.z = prm(u1.y, u1.x, 0x07060302u); rl.w = prm(u1.w, u1.z, 0x07060302u);
    h = *(short8*)&rh;
    l = *(short8*)&rl;
}

// 256x256 tile, 512 threads (8 waves, each 128x64), double-buffered LDS (128 KB).
// Interleaved-encoding schedule: ONE barrier + ONE vmcnt(0) per K-tile.
//   top: WAITVM(0) (own stage of cur done) + BARRIER (all waves' stages done)
//   read 24 b128 pairs -> unpack (v_perm) -> stage(nxt) -> 96 MFMA {hh, hl, lh}
// Overwrite safety: every ds_read of cur is consumed by an MFMA (compiler emits
// lgkmcnt before the MFMA), so reads are retired before the wave reaches the next
// top-barrier; stage into a given buffer happens >=1 barrier after its last read.
// MODE 0: T-enc = 1.5I - 0.5*C   MODE 1: C-enc   MODE 2: fp32 C*sqrt(normA)
template <int MODE>
__global__ __launch_bounds__(512, 2) void gemm_bt(const ushort* __restrict__ A,
                                                  const ushort* __restrict__ B,
                                                  ushort* __restrict__ Cenc,
                                                  float* __restrict__ Cout,
                                                  const float* __restrict__ norms) {
    __shared__ __attribute__((aligned(16))) ushort sm[2 * BUFE];  // 128 KB

    int f = blockIdx.x;           // 256 blocks: 64 matrices x 4 quadrant-tiles
    int xcd = f & 7;
    int g   = f >> 3;             // 0..31
    int b   = xcd + 8 * (g >> 2); // 8 matrices per XCD (4 co-tiles each)
    int t   = g & 3;
    int bm  = t >> 1;
    int bn  = t & 1;

    size_t matoff = (size_t)b * DIM * KENC;
    const ushort* Ag = A + matoff + (size_t)bm * BM * KENC;
    const ushort* Bg = B + matoff + (size_t)bn * BN * KENC;

    int tid = threadIdx.x;
    int wave = tid >> 6, lane = tid & 63;
    int lane15 = lane & 15, quad = lane >> 4;
    int wrow = (wave >> 2) * 128;   // 2 row-groups of 128
    int wcol = (wave & 3) * 64;     // 4 col-groups of 64
    int r7 = lane15 & 7;

    floatx4 acc[8][4];
    #pragma unroll
    for (int i = 0; i < 8; ++i)
        #pragma unroll
        for (int j = 0; j < 4; ++j)
            acc[i][j] = (floatx4){0.f, 0.f, 0.f, 0.f};

    stage_tile(sm, Ag, Bg, 0, tid);

    for (int kt = 0; kt < NKT; ++kt) {
        WAITVM(0);          // own 8 stage-loads of tile kt landed
        BARRIER();          // all waves' stages landed -> cur valid
        const ushort* cur = sm + (kt & 1) * BUFE;
        ushort* nxt = sm + ((kt + 1) & 1) * BUFE;
        const ushort* Abase = cur;
        const ushort* Bbase = cur + 16384;

        short8 ah[8], al[8], bh[4], bl[4];
        #pragma unroll
        for (int i = 0; i < 8; ++i)
            rdpair(&Abase[(wrow + i * 16 + lane15) * 64], quad, r7, ah[i], al[i]);
        #pragma unroll
        for (int j = 0; j < 4; ++j)
            rdpair(&Bbase[(wcol + j * 16 + lane15) * 64], quad, r7, bh[j], bl[j]);

        if (kt + 1 < NKT) stage_tile(nxt, Ag, Bg, (kt + 1) * BKT, tid);

        __builtin_amdgcn_s_setprio(1);
        #pragma unroll
        for (int i = 0; i < 8; ++i)
            #pragma unroll
            for (int j = 0; j < 4; ++j)
                acc[i][j] = __builtin_amdgcn_mfma_f32_16x16x32_bf16(ah[i], bh[j], acc[i][j], 0, 0, 0);
        #pragma unroll
        for (int i = 0; i < 8; ++i)
            #pragma unroll
            for (int j = 0; j < 4; ++j)
                acc[i][j] = __builtin_amdgcn_mfma_f32_16x16x32_bf16(ah[i], bl[j], acc[i][j], 0, 0, 0);
        #pragma unroll
        for (int i = 0; i < 8; ++i)
            #pragma unroll
            for (int j = 0; j < 4; ++j)
                acc[i][j] = __builtin_amdgcn_mfma_f32_16x16x32_bf16(al[i], bh[j], acc[i][j], 0, 0, 0);
        __builtin_amdgcn_s_setprio(0);
    }

    float scale = (MODE == 2) ? sqrtf(norms[b]) : 0.f;
    #pragma unroll
    for (int i = 0; i < 8; ++i) {
        int gr0 = bm * BM + wrow + i * 16 + quad * 4;
        #pragma unroll
        for (int j = 0; j < 4; ++j) {
            int gc = bn * BN + wcol + j * 16 + lane15;
            #pragma unroll
            for (int rr = 0; rr < 4; ++rr) {
                int gr = gr0 + rr;
                float cv = acc[i][j][rr];
                if (MODE == 2) {
                    Cout[(size_t)b * DIM * DIM + (size_t)gr * DIM + gc] = cv * scale;
                } else {
                    float v = (MODE == 0) ? ((gr == gc ? 1.5f : 0.0f) - 0.5f * cv) : cv;
                    ushort hi = f2bf(v);
                    ushort lo = f2bf(v - bf2f(hi));
                    *(uint32_t*)&Cenc[matoff + (size_t)gr * KENC + 2 * gc] =
                        (uint32_t)hi | ((uint32_t)lo << 16);
                }
            }
        }
    }
}

extern "C" void kernel_launch(void* const* d_in, const int* in_sizes, int n_in,
                              void* d_out, int out_size, void* d_ws, size_t ws_size,
                              hipStream_t stream) {
    const float* x = (const float*)d_in[0];  // d_in[1] = I, unused
    float* out = (float*)d_out;

    const size_t MATB = (size_t)BATCH * DIM * KENC * sizeof(ushort);  // 64 MB
    char* ws = (char*)d_ws;
    ushort* W0 = (ushort*)(ws + 0 * MATB);
    ushort* W1 = (ushort*)(ws + 1 * MATB);
    ushort* W2 = (ushort*)(ws + 2 * MATB);
    float* partial = (float*)(ws + 3 * MATB);          // 192 MB + 4 KB total
    float* norms   = (float*)(ws + 3 * MATB + 4096);
    ushort* D = (ushort*)d_out;  // encoded scratch slot #4; final fp32 GEMM overwrites last

    dim3 gblk(512);
    dim3 g1(256);

    norm_partial_kernel<<<dim3(16, BATCH), 256, 0, stream>>>(x, partial);
    init_kernel<<<dim3(256, BATCH), 256, 0, stream>>>(x, partial, norms, W0, W1);  // Y0->W0, T1(=Z1)->W1

    // iter 1: Y1 = Y0*T1 -> W2 ; Z1 = T1 (W1).             live: Y1=W2, Z1=W1   free: W0, D
    gemm_bt<1><<<g1, gblk, 0, stream>>>(W0, W1, W2, nullptr, nullptr);
    // iter 2: T2 = f(Z1*Y1) -> W0                          live: Y1=W2, Z1=W1, T2=W0   free: D
    gemm_bt<0><<<g1, gblk, 0, stream>>>(W1, W2, W0, nullptr, nullptr);
    gemm_bt<1><<<g1, gblk, 0, stream>>>(W2, W0, D, nullptr, nullptr);   // Y2 -> D
    gemm_bt<1><<<g1, gblk, 0, stream>>>(W0, W1, W2, nullptr, nullptr);  // Z2 = T2*Z1 -> W2
    // iter 3
    gemm_bt<0><<<g1, gblk, 0, stream>>>(W2, D, W0, nullptr, nullptr);   // T3 -> W0
    gemm_bt<1><<<g1, gblk, 0, stream>>>(D, W0, W1, nullptr, nullptr);   // Y3 -> W1
    gemm_bt<1><<<g1, gblk, 0, stream>>>(W0, W2, D, nullptr, nullptr);   // Z3 = T3*Z2 -> D
    // iter 4
    gemm_bt<0><<<g1, gblk, 0, stream>>>(D, W1, W0, nullptr, nullptr);   // T4 -> W0
    gemm_bt<1><<<g1, gblk, 0, stream>>>(W1, W0, W2, nullptr, nullptr);  // Y4 -> W2
    gemm_bt<1><<<g1, gblk, 0, stream>>>(W0, D, W1, nullptr, nullptr);   // Z4 = T4*Z3 -> W1
    // iter 5
    gemm_bt<0><<<g1, gblk, 0, stream>>>(W1, W2, W0, nullptr, nullptr);  // T5 -> W0
    gemm_bt<2><<<g1, gblk, 0, stream>>>(W2, W0, nullptr, out, norms);   // out = Y4*T5*sqrt(n)
}

// Round 8
// 754.503 us; speedup vs baseline: 1.0242x; 1.0242x over previous
//
#include <hip/hip_runtime.h>
#include <hip/hip_bf16.h>
#include <stdint.h>

#define DIM   512
#define BATCH 64
#define KENC  1024          // encoded row: [hi(512) | lo(512)]
#define BM    256
#define BN    256
#define BKT   32
#define NKT   16
#define BUFE  32768         // ushorts per LDS buffer (64 KB): 4 planes * 8192

typedef __attribute__((ext_vector_type(8))) short short8;
typedef __attribute__((ext_vector_type(4))) float floatx4;

__device__ __forceinline__ ushort f2bf(float f) {
    __hip_bfloat16 h = __float2bfloat16(f);
    return *(ushort*)&h;
}
__device__ __forceinline__ float bf2f(ushort u) {
    __hip_bfloat16 h = *(__hip_bfloat16*)&u;
    return (float)h;
}

typedef __attribute__((address_space(3))) uint32_t lds_u32;
typedef const __attribute__((address_space(1))) uint32_t glb_u32;
__device__ __forceinline__ void gload16(const ushort* g, ushort* l) {
    __builtin_amdgcn_global_load_lds((glb_u32*)g, (lds_u32*)l, 16, 0, 0);
}

#define WAITVM(N) asm volatile("s_waitcnt vmcnt(" #N ")" ::: "memory")
#define BARRIER() do { __builtin_amdgcn_s_barrier(); __builtin_amdgcn_sched_barrier(0); } while (0)

__global__ __launch_bounds__(256) void norm_partial_kernel(const float* __restrict__ x,
                                                           float* __restrict__ partial) {
    int b = blockIdx.y;
    int i = blockIdx.x;
    const float4* xv = (const float4*)(x + (size_t)b * DIM * DIM + (size_t)i * (DIM * DIM / 16));
    float s = 0.f;
    #pragma unroll
    for (int r = 0; r < 16; ++r) {
        float4 v = xv[r * 256 + threadIdx.x];
        s += v.x * v.x + v.y * v.y + v.z * v.z + v.w * v.w;
    }
    #pragma unroll
    for (int off = 32; off > 0; off >>= 1) s += __shfl_down(s, off, 64);
    __shared__ float red[4];
    int lane = threadIdx.x & 63, wid = threadIdx.x >> 6;
    if (lane == 0) red[wid] = s;
    __syncthreads();
    if (threadIdx.x == 0) partial[b * 16 + i] = red[0] + red[1] + red[2] + red[3];
}

__global__ __launch_bounds__(256) void init_kernel(const float* __restrict__ x,
                                                   const float* __restrict__ partial,
                                                   float* __restrict__ norms,
                                                   ushort* __restrict__ Yenc,
                                                   ushort* __restrict__ Tenc) {
    int b = blockIdx.y;
    float s = 0.f;
    #pragma unroll
    for (int p = 0; p < 16; ++p) s += partial[b * 16 + p];
    float nrm = sqrtf(s);
    if (blockIdx.x == 0 && threadIdx.x == 0) norms[b] = nrm;
    float inv = 1.0f / nrm;
    int idx = (blockIdx.x * 256 + threadIdx.x) * 4;
    int r = idx >> 9;
    int c = idx & 511;
    float4 v = *(const float4*)(x + (size_t)b * DIM * DIM + idx);
    float yv[4] = {v.x * inv, v.y * inv, v.z * inv, v.w * inv};
    size_t base = (size_t)b * DIM * KENC + (size_t)r * KENC;
    ushort yhi[4], ylo[4], thi[4], tlo[4];
    #pragma unroll
    for (int j = 0; j < 4; ++j) {
        float y = yv[j];
        yhi[j] = f2bf(y);
        ylo[j] = f2bf(y - bf2f(yhi[j]));
        float t = ((c + j) == r ? 1.5f : 0.0f) - 0.5f * y;
        thi[j] = f2bf(t);
        tlo[j] = f2bf(t - bf2f(thi[j]));
    }
    *(ushort4*)(Yenc + base + c)       = *(ushort4*)yhi;
    *(ushort4*)(Yenc + base + 512 + c) = *(ushort4*)ylo;
    *(ushort4*)(Tenc + base + c)       = *(ushort4*)thi;
    *(ushort4*)(Tenc + base + 512 + c) = *(ushort4*)tlo;
}

// Stage one K-tile's HI unit (Ahi plane @0, Bhi plane @16384): 4 gloads/thread.
// plane layout: 256 rows * 32 elem; physical chunk pc of row r holds logical
// chunk pc ^ ((r>>1)&3). LDS dest = base + vt*16B (lane-ordered, DMA-legal).
__device__ __forceinline__ void stage_hi(ushort* buf, const ushort* Ag, const ushort* Bg,
                                         int k0, int tid) {
    #pragma unroll
    for (int s = 0; s < 2; ++s) {
        int vt = tid + s * 512;
        int row = vt >> 2;
        int pc  = vt & 3;
        int kc  = ((pc ^ ((row >> 1) & 3)) << 3);
        const ushort* ar = Ag + (size_t)row * KENC + k0 + kc;
        const ushort* br = Bg + (size_t)row * KENC + k0 + kc;
        gload16(ar, &buf[vt * 8]);              // Ahi
        gload16(br, &buf[16384 + vt * 8]);      // Bhi
    }
}
// LO unit (Alo @8192, Blo @24576): 4 gloads/thread.
__device__ __forceinline__ void stage_lo(ushort* buf, const ushort* Ag, const ushort* Bg,
                                         int k0, int tid) {
    #pragma unroll
    for (int s = 0; s < 2; ++s) {
        int vt = tid + s * 512;
        int row = vt >> 2;
        int pc  = vt & 3;
        int kc  = ((pc ^ ((row >> 1) & 3)) << 3);
        const ushort* ar = Ag + (size_t)row * KENC + k0 + kc;
        const ushort* br = Bg + (size_t)row * KENC + k0 + kc;
        gload16(ar + 512, &buf[8192 + vt * 8]);   // Alo
        gload16(br + 512, &buf[24576 + vt * 8]);  // Blo
    }
}

__device__ __forceinline__ void store_enc(ushort* Cenc, size_t matoff, int gr, int gc, float v) {
    ushort hi = f2bf(v);
    ushort lo = f2bf(v - bf2f(hi));
    Cenc[matoff + (size_t)gr * KENC + gc] = hi;
    Cenc[matoff + (size_t)gr * KENC + 512 + gc] = lo;
}

// 256x256 tile, 512 threads (8 waves, each a 128x64 sub-tile), double-buffered LDS.
// R3-base with MERGED SYNC: exactly ONE barrier + ONE vmcnt per K-tile (vs R3's
// 2+2). Tile structure:
//   A: stage FULL next tile (8 gloads); 32 MFMA hh on regs preloaded last tile
//   B: read bl(4), al(8) from cur; 64 MFMA (hl, lh)
//   WAITVM(0)   <- drains stage(kt+1); issued ~96 MFMAs ago so latency long
//                  covered (the "never vmcnt(0)" rule targets RECENT loads)
//   BARRIER     <- the single global read/write separator (see audit below)
//   C: preload next tile's ah(8), bh(4) from nxt (all frag regs dead here)
// Hazard audit (1 barrier suffices):
//  - overwrite: stage(kt+2) [next iter A] writes buffer kt&1; its last readers
//    are B(kt) reads + C(kt-1) preloads, all lgkm-drained by their consuming
//    MFMAs BEFORE each wave reaches the end-of-kt barrier; stage(kt+2) is
//    issued only AFTER that barrier by every wave. Separated globally.
//  - publish: C(kt) reads buffer kt+1 only after own WAITVM(0) (own DMA done)
//    AND the barrier (every wave's WAITVM(0) precedes its arrival), so all
//    512 threads' stage loads have landed.
// Register budget: frags ah8+bh4+bl4+al8 = 96 VGPR + acc 128 => ~240, no spill
// (round-4 lesson: never exceed ~250 at launch_bounds(512,2)).
// MODE 0: T-enc = 1.5I - 0.5*C   MODE 1: C-enc   MODE 2: fp32 C*sqrt(normA)
template <int MODE>
__global__ __launch_bounds__(512, 2) void gemm_bt(const ushort* __restrict__ A,
                                                  const ushort* __restrict__ B,
                                                  ushort* __restrict__ Cenc,
                                                  float* __restrict__ Cout,
                                                  const float* __restrict__ norms) {
    __shared__ __attribute__((aligned(16))) ushort sm[2 * BUFE];  // 128 KB

    int f = blockIdx.x;           // 256 blocks: 64 matrices x 4 quadrant-tiles
    int xcd = f & 7;
    int g   = f >> 3;             // 0..31
    int b   = xcd + 8 * (g >> 2); // 8 matrices per XCD (4 co-tiles each)
    int t   = g & 3;
    int bm  = t >> 1;
    int bn  = t & 1;

    size_t matoff = (size_t)b * DIM * KENC;
    const ushort* Ag = A + matoff + (size_t)bm * BM * KENC;
    const ushort* Bg = B + matoff + (size_t)bn * BN * KENC;

    int tid = threadIdx.x;
    int wave = tid >> 6, lane = tid & 63;
    int lane15 = lane & 15, quad = lane >> 4;
    int wrow = (wave >> 2) * 128;   // 2 row-groups of 128
    int wcol = (wave & 3) * 64;     // 4 col-groups of 64
    int s2 = (lane15 >> 1) & 3;
    int fo = ((quad ^ s2) << 3);

    floatx4 acc[8][4];
    #pragma unroll
    for (int i = 0; i < 8; ++i)
        #pragma unroll
        for (int j = 0; j < 4; ++j)
            acc[i][j] = (floatx4){0.f, 0.f, 0.f, 0.f};

    // prologue: stage tile 0 fully; publish; preload ah/bh for the first A-region
    stage_hi(sm, Ag, Bg, 0, tid);
    stage_lo(sm, Ag, Bg, 0, tid);
    WAITVM(0);
    BARRIER();

    short8 ah[8], bh[4], bl[4], al[8];
    #pragma unroll
    for (int i = 0; i < 8; ++i)
        ah[i] = *(const short8*)&sm[(wrow + i * 16 + lane15) * BKT + fo];
    #pragma unroll
    for (int j = 0; j < 4; ++j)
        bh[j] = *(const short8*)&sm[16384 + (wcol + j * 16 + lane15) * BKT + fo];

    for (int kt = 0; kt < NKT; ++kt) {
        const ushort* cur = sm + (kt & 1) * BUFE;
        ushort* nxt = sm + ((kt + 1) & 1) * BUFE;
        const ushort* Asl = cur + 8192;
        const ushort* Bsl = cur + 24576;
        bool pre = (kt + 1 < NKT);

        // ---- Region A: stage full next tile; 32 MFMA hh (preloaded regs) ----
        if (pre) {
            stage_hi(nxt, Ag, Bg, (kt + 1) * BKT, tid);
            stage_lo(nxt, Ag, Bg, (kt + 1) * BKT, tid);
        }
        __builtin_amdgcn_s_setprio(1);
        #pragma unroll
        for (int i = 0; i < 8; ++i)
            #pragma unroll
            for (int j = 0; j < 4; ++j)
                acc[i][j] = __builtin_amdgcn_mfma_f32_16x16x32_bf16(ah[i], bh[j], acc[i][j], 0, 0, 0);
        __builtin_amdgcn_s_setprio(0);

        // ---- Region B: read bl, al from cur; 64 MFMA (hl then lh) ----
        #pragma unroll
        for (int j = 0; j < 4; ++j)
            bl[j] = *(const short8*)&Bsl[(wcol + j * 16 + lane15) * BKT + fo];
        #pragma unroll
        for (int i = 0; i < 8; ++i)
            al[i] = *(const short8*)&Asl[(wrow + i * 16 + lane15) * BKT + fo];
        __builtin_amdgcn_s_setprio(1);
        #pragma unroll
        for (int i = 0; i < 8; ++i)
            #pragma unroll
            for (int j = 0; j < 4; ++j)
                acc[i][j] = __builtin_amdgcn_mfma_f32_16x16x32_bf16(ah[i], bl[j], acc[i][j], 0, 0, 0);
        #pragma unroll
        for (int i = 0; i < 8; ++i)
            #pragma unroll
            for (int j = 0; j < 4; ++j)
                acc[i][j] = __builtin_amdgcn_mfma_f32_16x16x32_bf16(al[i], bh[j], acc[i][j], 0, 0, 0);
        __builtin_amdgcn_s_setprio(0);

        if (pre) {
            // single sync pair per tile: stage(kt+1) was issued ~96 MFMAs ago
            WAITVM(0);
            BARRIER();
            // ---- Region C: preload next tile's ah/bh (frag regs dead) ----
            #pragma unroll
            for (int i = 0; i < 8; ++i)
                ah[i] = *(const short8*)&nxt[(wrow + i * 16 + lane15) * BKT + fo];
            #pragma unroll
            for (int j = 0; j < 4; ++j)
                bh[j] = *(const short8*)&nxt[16384 + (wcol + j * 16 + lane15) * BKT + fo];
        }
    }

    float scale = (MODE == 2) ? sqrtf(norms[b]) : 0.f;
    #pragma unroll
    for (int i = 0; i < 8; ++i) {
        int gr0 = bm * BM + wrow + i * 16 + quad * 4;
        #pragma unroll
        for (int j = 0; j < 4; ++j) {
            int gc = bn * BN + wcol + j * 16 + lane15;
            #pragma unroll
            for (int rr = 0; rr < 4; ++rr) {
                int gr = gr0 + rr;
                float cv = acc[i][j][rr];
                if (MODE == 0) {
                    store_enc(Cenc, matoff, gr, gc, (gr == gc ? 1.5f : 0.0f) - 0.5f * cv);
                } else if (MODE == 1) {
                    store_enc(Cenc, matoff, gr, gc, cv);
                } else {
                    Cout[(size_t)b * DIM * DIM + (size_t)gr * DIM + gc] = cv * scale;
                }
            }
        }
    }
}

extern "C" void kernel_launch(void* const* d_in, const int* in_sizes, int n_in,
                              void* d_out, int out_size, void* d_ws, size_t ws_size,
                              hipStream_t stream) {
    const float* x = (const float*)d_in[0];  // d_in[1] = I, unused
    float* out = (float*)d_out;

    const size_t MATB = (size_t)BATCH * DIM * KENC * sizeof(ushort);  // 64 MB
    char* ws = (char*)d_ws;
    ushort* W0 = (ushort*)(ws + 0 * MATB);
    ushort* W1 = (ushort*)(ws + 1 * MATB);
    ushort* W2 = (ushort*)(ws + 2 * MATB);
    float* partial = (float*)(ws + 3 * MATB);          // 192 MB + 4 KB total
    float* norms   = (float*)(ws + 3 * MATB + 4096);
    ushort* D = (ushort*)d_out;  // encoded scratch slot #4; final fp32 GEMM overwrites last

    dim3 gblk(512);
    dim3 g1(256);

    norm_partial_kernel<<<dim3(16, BATCH), 256, 0, stream>>>(x, partial);
    init_kernel<<<dim3(256, BATCH), 256, 0, stream>>>(x, partial, norms, W0, W1);  // Y0->W0, T1(=Z1)->W1

    // iter 1: Y1 = Y0*T1 -> W2 ; Z1 = T1 (W1).             live: Y1=W2, Z1=W1   free: W0, D
    gemm_bt<1><<<g1, gblk, 0, stream>>>(W0, W1, W2, nullptr, nullptr);
    // iter 2: T2 = f(Z1*Y1) -> W0                          live: Y1=W2, Z1=W1, T2=W0   free: D
    gemm_bt<0><<<g1, gblk, 0, stream>>>(W1, W2, W0, nullptr, nullptr);
    gemm_bt<1><<<g1, gblk, 0, stream>>>(W2, W0, D, nullptr, nullptr);   // Y2 -> D
    gemm_bt<1><<<g1, gblk, 0, stream>>>(W0, W1, W2, nullptr, nullptr);  // Z2 = T2*Z1 -> W2
    // iter 3
    gemm_bt<0><<<g1, gblk, 0, stream>>>(W2, D, W0, nullptr, nullptr);   // T3 -> W0
    gemm_bt<1><<<g1, gblk, 0, stream>>>(D, W0, W1, nullptr, nullptr);   // Y3 -> W1
    gemm_bt<1><<<g1, gblk, 0, stream>>>(W0, W2, D, nullptr, nullptr);   // Z3 = T3*Z2 -> D
    // iter 4
    gemm_bt<0><<<g1, gblk, 0, stream>>>(D, W1, W0, nullptr, nullptr);   // T4 -> W0
    gemm_bt<1><<<g1, gblk, 0, stream>>>(W1, W0, W2, nullptr, nullptr);  // Y4 -> W2
    gemm_bt<1><<<g1, gblk, 0, stream>>>(W0, D, W1, nullptr, nullptr);   // Z4 = T4*Z3 -> W1
    // iter 5
    gemm_bt<0><<<g1, gblk, 0, stream>>>(W1, W2, W0, nullptr, nullptr);  // T5 -> W0
    gemm_bt<2><<<g1, gblk, 0, stream>>>(W2, W0, nullptr, out, norms);   // out = Y4*T5*sqrt(n)
}